// Round 1
// baseline (601.402 us; speedup 1.0000x reference)
//
#include <hip/hip_runtime.h>
#include <cstdint>
#include <cstddef>

#define H 512
#define W 512
#define NPIX (H * W)          // 262144 = 2^18
#define TOPK 2048
#define CAND_CAP 4096
#define NBATCH 2

struct Tap {
    int x0, x1, y0, y1;
    float wx, wy;
    float pad0, pad1;
};

// 7x7 max with H-split at 256 (reference _maxpool_split), -inf padding
__device__ __forceinline__ float mp7f(const float* m, int y, int x) {
    int ylo = y - 3, yhi = y + 3;
    if (y < 256) { if (ylo < 0) ylo = 0; if (yhi > 255) yhi = 255; }
    else         { if (ylo < 256) ylo = 256; if (yhi > 511) yhi = 511; }
    int xlo = x - 3; if (xlo < 0) xlo = 0;
    int xhi = x + 3; if (xhi > 511) xhi = 511;
    float v = -INFINITY;
    for (int yy = ylo; yy <= yhi; ++yy) {
        const float* row = m + yy * W;
        for (int xx = xlo; xx <= xhi; ++xx) v = fmaxf(v, row[xx]);
    }
    return v;
}

__device__ __forceinline__ int any7(const unsigned char* m, int y, int x) {
    int ylo = y - 3, yhi = y + 3;
    if (y < 256) { if (ylo < 0) ylo = 0; if (yhi > 255) yhi = 255; }
    else         { if (ylo < 256) ylo = 256; if (yhi > 511) yhi = 511; }
    int xlo = x - 3; if (xlo < 0) xlo = 0;
    int xhi = x + 3; if (xhi > 511) xhi = 511;
    int v = 0;
    for (int yy = ylo; yy <= yhi; ++yy) {
        const unsigned char* row = m + yy * W;
        for (int xx = xlo; xx <= xhi; ++xx) v |= row[xx];
    }
    return v ? 1 : 0;
}

// K1: mm0 = (s == maxpool_split(s))
__global__ void k_mm0(const float* __restrict__ s, unsigned char* __restrict__ mm0) {
    int t = blockIdx.x * blockDim.x + threadIdx.x;
    if (t >= NBATCH * NPIX) return;
    int b = t >> 18;
    int r = t & (NPIX - 1);
    int y = r >> 9, x = r & 511;
    const float* sb = s + (size_t)b * NPIX;
    mm0[t] = (sb[r] == mp7f(sb, y, x)) ? 1 : 0;
}

// K2/K4: sm = dilate(mm) > 0 ; ss = sm ? 0 : s
__global__ void k_suppress(const float* __restrict__ s, const unsigned char* __restrict__ mm,
                           unsigned char* __restrict__ sm, float* __restrict__ ss) {
    int t = blockIdx.x * blockDim.x + threadIdx.x;
    if (t >= NBATCH * NPIX) return;
    int b = t >> 18;
    int r = t & (NPIX - 1);
    int y = r >> 9, x = r & 511;
    int a = any7(mm + (size_t)b * NPIX, y, x);
    sm[t] = (unsigned char)a;
    ss[t] = a ? 0.0f : s[t];
}

// K3: mm_out = mm_in | ((ss == maxpool_split(ss)) & ~sm)
__global__ void k_update(const float* __restrict__ ss, const unsigned char* __restrict__ mmin,
                         const unsigned char* __restrict__ sm, unsigned char* __restrict__ mmout) {
    int t = blockIdx.x * blockDim.x + threadIdx.x;
    if (t >= NBATCH * NPIX) return;
    int b = t >> 18;
    int r = t & (NPIX - 1);
    int y = r >> 9, x = r & 511;
    const float* ssb = ss + (size_t)b * NPIX;
    int nm = (ssb[r] == mp7f(ssb, y, x)) ? 1 : 0;
    mmout[t] = (unsigned char)(mmin[t] | (nm & (1 - (int)sm[t])));
}

// K5: nms = (mm2 & border) ? s : 0  where mm2 = mm1 | (nm2 & ~sm2)
__global__ void k_final(const float* __restrict__ s, const float* __restrict__ ss,
                        const unsigned char* __restrict__ mm, const unsigned char* __restrict__ sm,
                        float* __restrict__ nms) {
    int t = blockIdx.x * blockDim.x + threadIdx.x;
    if (t >= NBATCH * NPIX) return;
    int b = t >> 18;
    int r = t & (NPIX - 1);
    int y = r >> 9, x = r & 511;
    const float* ssb = ss + (size_t)b * NPIX;
    int nm2 = (ssb[r] == mp7f(ssb, y, x)) ? 1 : 0;
    int mm2 = mm[t] | (nm2 & (1 - (int)sm[t]));
    bool border = (y >= 3) && (y < 510) && (x >= 3) && (x < 510);
    nms[t] = (mm2 && border) ? s[t] : 0.0f;
}

// K6: histogram of top-16 bits of float bit pattern (monotone for positives)
__global__ void k_hist(const float* __restrict__ nms, unsigned int* __restrict__ hist) {
    int t = blockIdx.x * blockDim.x + threadIdx.x;
    if (t >= NBATCH * NPIX) return;
    float v = nms[t];
    if (v > 0.0f) {
        int b = t >> 18;
        unsigned int key = __float_as_uint(v);
        atomicAdd(&hist[b * 65536 + (key >> 16)], 1u);
    }
}

// K7: find highest bucket tb such that count(buckets >= tb) >= TOPK
__global__ void k_thresh(const unsigned int* __restrict__ hist, unsigned int* __restrict__ tb) {
    int b = blockIdx.x;
    const unsigned int* h = hist + b * 65536;
    __shared__ unsigned int part[1024];
    int t = threadIdx.x;
    unsigned int acc = 0;
    for (int i = 0; i < 64; ++i) acc += h[t * 64 + i];
    part[t] = acc;
    __syncthreads();
    if (t == 0) {
        unsigned int cum = 0;
        int chunk = 1023;
        for (; chunk >= 0; --chunk) {
            if (cum + part[chunk] >= TOPK) break;
            cum += part[chunk];
        }
        unsigned int bin = 0;
        if (chunk >= 0) {
            int bb = chunk * 64 + 63;
            for (; bb >= chunk * 64; --bb) {
                cum += h[bb];
                if (cum >= TOPK) break;
            }
            if (bb < chunk * 64) bb = chunk * 64;
            bin = (unsigned int)bb;
        }
        tb[b] = bin;
    }
}

// K8: collect candidates with bucket >= tb as (valbits<<32)|~pix  (tie -> smaller idx first)
__global__ void k_collect(const float* __restrict__ nms, const unsigned int* __restrict__ tb,
                          unsigned long long* __restrict__ cand, unsigned int* __restrict__ cnt) {
    int t = blockIdx.x * blockDim.x + threadIdx.x;
    if (t >= NBATCH * NPIX) return;
    float v = nms[t];
    if (v > 0.0f) {
        int b = t >> 18;
        unsigned int key = __float_as_uint(v);
        if ((key >> 16) >= tb[b]) {
            unsigned int pos = atomicAdd(&cnt[b], 1u);
            if (pos < CAND_CAP) {
                unsigned int pix = (unsigned int)(t & (NPIX - 1));
                cand[b * CAND_CAP + pos] =
                    ((unsigned long long)key << 32) | (unsigned long long)(~pix);
            }
        }
    }
}

// K9: one block per batch, bitonic sort 4096 composites descending, emit top 2048 pixel indices
__global__ void k_sort(const unsigned long long* __restrict__ cand, const unsigned int* __restrict__ cnt,
                       int* __restrict__ kpts) {
    int b = blockIdx.x;
    __shared__ unsigned long long sk[CAND_CAP];
    int tid = threadIdx.x;                 // 1024 threads
    unsigned int n = cnt[b];
    if (n > CAND_CAP) n = CAND_CAP;
    for (int i = tid; i < CAND_CAP; i += 1024)
        sk[i] = (i < (int)n) ? cand[b * CAND_CAP + i] : 0ULL;
    __syncthreads();
    for (int k = 2; k <= CAND_CAP; k <<= 1) {
        for (int j = k >> 1; j > 0; j >>= 1) {
            for (int i = tid; i < CAND_CAP; i += 1024) {
                int ixj = i ^ j;
                if (ixj > i) {
                    unsigned long long a = sk[i], c = sk[ixj];
                    bool descSeg = ((i & k) == 0);
                    bool doSwap = descSeg ? (a < c) : (a > c);
                    if (doSwap) { sk[i] = c; sk[ixj] = a; }
                }
            }
            __syncthreads();
        }
    }
    for (int r = tid; r < TOPK; r += 1024) {
        unsigned long long c = sk[r];
        unsigned int pix = ~(unsigned int)(c & 0xFFFFFFFFULL);
        kpts[b * TOPK + r] = (int)pix;
    }
}

// K10: per-keypoint 5x5 soft-argmax, disp, normalized kxy, score bilinear, tap cache
__global__ void k_soft(const float* __restrict__ s, const int* __restrict__ kpts,
                       float* __restrict__ out_kxy, float* __restrict__ out_sc,
                       float* __restrict__ out_disp, Tap* __restrict__ taps) {
    int t = blockIdx.x * blockDim.x + threadIdx.x;
    if (t >= NBATCH * TOPK) return;
    int b = t >> 11;
    int pix = kpts[t];
    int ky = (pix >> 9) & 511, kx = pix & 511;
    const float* sb = s + (size_t)b * NPIX;

    float p[25];
    float maxv = -INFINITY;
    #pragma unroll
    for (int i = 0; i < 5; ++i)
        #pragma unroll
        for (int j = 0; j < 5; ++j) {
            float v = sb[(ky - 2 + i) * W + (kx - 2 + j)];
            p[i * 5 + j] = v;
            maxv = fmaxf(maxv, v);
        }
    float e[25];
    float ssum = 0.0f, sx = 0.0f, sy = 0.0f;
    #pragma unroll
    for (int i = 0; i < 5; ++i)
        #pragma unroll
        for (int j = 0; j < 5; ++j) {
            float ev = expf((p[i * 5 + j] - maxv) / 0.1f);
            e[i * 5 + j] = ev;
            ssum += ev;
            sx += ev * (float)(j - 2);
            sy += ev * (float)(i - 2);
        }
    float xr = sx / ssum, yr = sy / ssum;
    float acc = 0.0f;
    #pragma unroll
    for (int i = 0; i < 5; ++i)
        #pragma unroll
        for (int j = 0; j < 5; ++j) {
            float dx = ((float)(j - 2) - xr) * 0.5f;
            float dy = ((float)(i - 2) - yr) * 0.5f;
            acc += e[i * 5 + j] * (dx * dx + dy * dy);
        }
    float disp = acc / ssum;

    float nx = ((float)kx + xr) / 511.0f * 2.0f - 1.0f;
    float ny = ((float)ky + yr) / 511.0f * 2.0f - 1.0f;
    out_kxy[t * 2 + 0] = nx;
    out_kxy[t * 2 + 1] = ny;
    out_disp[t] = disp;

    // bilinear of scores at (nx,ny) exactly as reference _bilinear
    float xp = (nx + 1.0f) * 0.5f * 511.0f;
    float yp = (ny + 1.0f) * 0.5f * 511.0f;
    float x0 = floorf(xp), y0 = floorf(yp);
    float wxf = xp - x0, wyf = yp - y0;
    int x0i = (int)fminf(fmaxf(x0, 0.0f), 511.0f);
    int x1i = (int)fminf(fmaxf(x0 + 1.0f, 0.0f), 511.0f);
    int y0i = (int)fminf(fmaxf(y0, 0.0f), 511.0f);
    int y1i = (int)fminf(fmaxf(y0 + 1.0f, 0.0f), 511.0f);
    float v00 = sb[y0i * W + x0i], v01 = sb[y0i * W + x1i];
    float v10 = sb[y1i * W + x0i], v11 = sb[y1i * W + x1i];
    out_sc[t] = v00 * (1.0f - wxf) * (1.0f - wyf) + v01 * wxf * (1.0f - wyf)
              + v10 * (1.0f - wxf) * wyf + v11 * wxf * wyf;

    Tap tp;
    tp.x0 = x0i; tp.x1 = x1i; tp.y0 = y0i; tp.y1 = y1i;
    tp.wx = wxf; tp.wy = wyf; tp.pad0 = 0.0f; tp.pad1 = 0.0f;
    taps[t] = tp;
}

// K11: one block per keypoint, 128 threads = 128 channels; bilinear + L2 normalize
__global__ void k_desc(const float* __restrict__ dmap, const Tap* __restrict__ taps,
                       float* __restrict__ out_desc) {
    int t = blockIdx.x;          // 0..4095
    int b = t >> 11;
    int c = threadIdx.x;         // 0..127
    Tap tp = taps[t];
    const float* db = dmap + ((size_t)(b * 128 + c)) * NPIX;
    float w00 = (1.0f - tp.wx) * (1.0f - tp.wy);
    float w01 = tp.wx * (1.0f - tp.wy);
    float w10 = (1.0f - tp.wx) * tp.wy;
    float w11 = tp.wx * tp.wy;
    float v = db[tp.y0 * W + tp.x0] * w00 + db[tp.y0 * W + tp.x1] * w01
            + db[tp.y1 * W + tp.x0] * w10 + db[tp.y1 * W + tp.x1] * w11;

    float sq = v * v;
    #pragma unroll
    for (int m = 32; m >= 1; m >>= 1) sq += __shfl_xor(sq, m, 64);
    __shared__ float red[2];
    int wave = c >> 6, lane = c & 63;
    if (lane == 0) red[wave] = sq;
    __syncthreads();
    float tot = red[0] + red[1];
    float nrm = sqrtf(tot);
    float sc = 1.0f / fmaxf(nrm, 1e-12f);
    out_desc[(size_t)t * 128 + c] = v * sc;
}

extern "C" void kernel_launch(void* const* d_in, const int* in_sizes, int n_in,
                              void* d_out, int out_size, void* d_ws, size_t ws_size,
                              hipStream_t stream) {
    const float* s    = (const float*)d_in[0];   // (2,1,512,512)
    const float* dmap = (const float*)d_in[1];   // (2,128,512,512)
    float* out = (float*)d_out;
    float* out_kxy  = out;                          // 2*2048*2 = 8192
    float* out_desc = out + 8192;                   // 2*2048*128 = 524288
    float* out_sc   = out + 8192 + 524288;          // 2*2048 = 4096
    float* out_disp = out_sc + 4096;                // 2*2048 = 4096

    char* w = (char*)d_ws;
    float* nms           = (float*)w;          w += (size_t)NBATCH * NPIX * 4;
    float* ssb           = (float*)w;          w += (size_t)NBATCH * NPIX * 4;
    unsigned char* mm0   = (unsigned char*)w;  w += (size_t)NBATCH * NPIX;
    unsigned char* mm1   = (unsigned char*)w;  w += (size_t)NBATCH * NPIX;
    unsigned char* smb   = (unsigned char*)w;  w += (size_t)NBATCH * NPIX;
    unsigned int* hist   = (unsigned int*)w;   w += (size_t)NBATCH * 65536 * 4;
    unsigned long long* cand = (unsigned long long*)w; w += (size_t)NBATCH * CAND_CAP * 8;
    unsigned int* cnt    = (unsigned int*)w;   w += 256;
    unsigned int* tb     = (unsigned int*)w;   w += 256;
    int* kpts            = (int*)w;            w += (size_t)NBATCH * TOPK * 4;
    Tap* taps            = (Tap*)w;            w += (size_t)NBATCH * TOPK * sizeof(Tap);

    hipMemsetAsync(hist, 0, (size_t)NBATCH * 65536 * 4, stream);
    hipMemsetAsync(cnt, 0, 256, stream);

    dim3 blk(256);
    dim3 grd((NBATCH * NPIX) / 256);

    k_mm0<<<grd, blk, 0, stream>>>(s, mm0);
    k_suppress<<<grd, blk, 0, stream>>>(s, mm0, smb, ssb);
    k_update<<<grd, blk, 0, stream>>>(ssb, mm0, smb, mm1);
    k_suppress<<<grd, blk, 0, stream>>>(s, mm1, smb, ssb);
    k_final<<<grd, blk, 0, stream>>>(s, ssb, mm1, smb, nms);
    k_hist<<<grd, blk, 0, stream>>>(nms, hist);
    k_thresh<<<dim3(NBATCH), dim3(1024), 0, stream>>>(hist, tb);
    k_collect<<<grd, blk, 0, stream>>>(nms, tb, cand, cnt);
    k_sort<<<dim3(NBATCH), dim3(1024), 0, stream>>>(cand, cnt, kpts);
    k_soft<<<dim3((NBATCH * TOPK) / 256), dim3(256), 0, stream>>>(s, kpts, out_kxy, out_sc, out_disp, taps);
    k_desc<<<dim3(NBATCH * TOPK), dim3(128), 0, stream>>>(dmap, taps, out_desc);
}

// Round 2
// 509.916 us; speedup vs baseline: 1.1794x; 1.1794x over previous
//
#include <hip/hip_runtime.h>
#include <cstdint>
#include <cstddef>

#define H 512
#define W 512
#define NPIX (H * W)          // 262144 = 2^18
#define TOPK 2048
#define CAND_CAP 4096
#define NBATCH 2

#define RG 62                 // NMS tile region (32 + 2*15 halo)
#define RS 64                 // padded LDS row stride
#define NTOT (RG * RS)        // 3968

struct Tap {
    int x0, x1, y0, y1;
    float wx, wy;
    float pad0, pad1;
};

// ---------------------------------------------------------------------------
// K0: zero hist + cnt in one dispatch
__global__ void k_zero(unsigned int* __restrict__ hist, unsigned int* __restrict__ cnt) {
    int i = blockIdx.x * 256 + threadIdx.x;
    if (i < NBATCH * 65536) hist[i] = 0;
    if (i < 8) cnt[i] = 0;
}

// ---------------------------------------------------------------------------
// K1: fully-fused simple_nms (5 maxpool-chain passes) in LDS, 32x32 output
// tile with 15-px halo. Separable 7-tap row/col max. Bit-exact vs reference:
// -inf padding == reduce_window edge clipping; H-split at 256 respected
// because tiles never straddle it and out-of-half rows are padded.
// Emits nms map + histogram of float-bit top-16 prefixes (monotone for v>0).
__global__ __launch_bounds__(256) void k_nms_fused(
        const float* __restrict__ s, float* __restrict__ nms,
        unsigned int* __restrict__ hist) {
    __shared__ float A[NTOT];            // s region (kept whole kernel)
    __shared__ float Bf[NTOT];           // ss
    __shared__ float Cf[NTOT];           // row-max temp
    __shared__ unsigned char Mmm[NTOT];  // mm
    __shared__ unsigned char Msm[NTOT];  // sm
    __shared__ unsigned char Mt[NTOT];   // row-OR temp

    const int tid = threadIdx.x;
    const int b = blockIdx.z;
    const int gx0 = blockIdx.x * 32 - 15;
    const int gy0 = blockIdx.y * 32 - 15;
    const int h0 = (blockIdx.y < 8) ? 0 : 256;
    const int h1 = h0 + 256;
    const float* sb = s + (size_t)b * NPIX;

    // load region with -inf padding (outside image or outside H-half)
    for (int i = tid; i < NTOT; i += 256) {
        int x = i & 63, y = i >> 6;
        float v = -INFINITY;
        int gx = gx0 + x, gy = gy0 + y;
        if (x < RG && gx >= 0 && gx < W && gy >= h0 && gy < h1)
            v = sb[gy * W + gx];
        A[i] = v;
    }
    __syncthreads();

    // rowmax7(A) -> Cf : x in [3,59), all y
    for (int i = tid; i < NTOT; i += 256) {
        int x = i & 63;
        if (x >= 3 && x < 59) {
            float m = A[i - 3];
            m = fmaxf(m, A[i - 2]); m = fmaxf(m, A[i - 1]); m = fmaxf(m, A[i]);
            m = fmaxf(m, A[i + 1]); m = fmaxf(m, A[i + 2]); m = fmaxf(m, A[i + 3]);
            Cf[i] = m;
        }
    }
    __syncthreads();

    // mm0 = (A == colmax7(Cf)) : rect [3,59)^2
    for (int i = tid; i < NTOT; i += 256) {
        int x = i & 63, y = i >> 6;
        if (x >= 3 && x < 59 && y >= 3 && y < 59) {
            float m = Cf[i - 3 * RS];
            m = fmaxf(m, Cf[i - 2 * RS]); m = fmaxf(m, Cf[i - RS]);
            m = fmaxf(m, Cf[i]);
            m = fmaxf(m, Cf[i + RS]); m = fmaxf(m, Cf[i + 2 * RS]);
            m = fmaxf(m, Cf[i + 3 * RS]);
            Mmm[i] = (A[i] == m) ? 1 : 0;
        }
    }
    __syncthreads();

    for (int it = 0; it < 2; ++it) {
        const int lo1 = 6 + 6 * it, hi1 = RG - lo1;   // after dilate
        const int lo0 = lo1 - 3,    hi0 = RG - lo0;   // mm-valid rect
        const int lo2 = lo1 + 3,    hi2 = RG - lo2;   // after pool

        // rowOR7(Mmm) -> Mt : x in [lo1,hi1), y in [lo0,hi0)
        for (int i = tid; i < NTOT; i += 256) {
            int x = i & 63, y = i >> 6;
            if (x >= lo1 && x < hi1 && y >= lo0 && y < hi0) {
                Mt[i] = (unsigned char)(Mmm[i - 3] | Mmm[i - 2] | Mmm[i - 1] |
                                        Mmm[i] | Mmm[i + 1] | Mmm[i + 2] | Mmm[i + 3]);
            }
        }
        __syncthreads();

        // sm = colOR7(Mt); ss = sm ? 0 : s : rect [lo1,hi1)^2
        for (int i = tid; i < NTOT; i += 256) {
            int x = i & 63, y = i >> 6;
            if (x >= lo1 && x < hi1 && y >= lo1 && y < hi1) {
                unsigned char o = (unsigned char)(Mt[i - 3 * RS] | Mt[i - 2 * RS] |
                                                  Mt[i - RS] | Mt[i] | Mt[i + RS] |
                                                  Mt[i + 2 * RS] | Mt[i + 3 * RS]);
                Msm[i] = o;
                Bf[i] = o ? 0.0f : A[i];
            }
        }
        __syncthreads();

        // rowmax7(Bf) -> Cf : x in [lo2,hi2), y in [lo1,hi1)
        for (int i = tid; i < NTOT; i += 256) {
            int x = i & 63, y = i >> 6;
            if (x >= lo2 && x < hi2 && y >= lo1 && y < hi1) {
                float m = Bf[i - 3];
                m = fmaxf(m, Bf[i - 2]); m = fmaxf(m, Bf[i - 1]); m = fmaxf(m, Bf[i]);
                m = fmaxf(m, Bf[i + 1]); m = fmaxf(m, Bf[i + 2]); m = fmaxf(m, Bf[i + 3]);
                Cf[i] = m;
            }
        }
        __syncthreads();

        if (it == 0) {
            // mm |= (Bf == colmax7(Cf)) & ~sm : rect [lo2,hi2)^2
            for (int i = tid; i < NTOT; i += 256) {
                int x = i & 63, y = i >> 6;
                if (x >= lo2 && x < hi2 && y >= lo2 && y < hi2) {
                    float m = Cf[i - 3 * RS];
                    m = fmaxf(m, Cf[i - 2 * RS]); m = fmaxf(m, Cf[i - RS]);
                    m = fmaxf(m, Cf[i]);
                    m = fmaxf(m, Cf[i + RS]); m = fmaxf(m, Cf[i + 2 * RS]);
                    m = fmaxf(m, Cf[i + 3 * RS]);
                    int nm = (Bf[i] == m) ? 1 : 0;
                    Mmm[i] = (unsigned char)(Mmm[i] | (nm & (1 - (int)Msm[i])));
                }
            }
            __syncthreads();
        } else {
            // final: mm2 = mm | nm2 & ~sm2; nms = (mm2 & border) ? s : 0
            for (int i = tid; i < NTOT; i += 256) {
                int x = i & 63, y = i >> 6;
                if (x >= 15 && x < 47 && y >= 15 && y < 47) {
                    float m = Cf[i - 3 * RS];
                    m = fmaxf(m, Cf[i - 2 * RS]); m = fmaxf(m, Cf[i - RS]);
                    m = fmaxf(m, Cf[i]);
                    m = fmaxf(m, Cf[i + RS]); m = fmaxf(m, Cf[i + 2 * RS]);
                    m = fmaxf(m, Cf[i + 3 * RS]);
                    int nm = (Bf[i] == m) ? 1 : 0;
                    int mm2 = Mmm[i] | (nm & (1 - (int)Msm[i]));
                    int gx = gx0 + x, gy = gy0 + y;
                    bool border = (gx >= 3) && (gx < 510) && (gy >= 3) && (gy < 510);
                    float v = (mm2 && border) ? A[i] : 0.0f;
                    nms[(size_t)b * NPIX + gy * W + gx] = v;
                    if (v > 0.0f) {
                        unsigned int key = __float_as_uint(v);
                        atomicAdd(&hist[b * 65536 + (key >> 16)], 1u);
                    }
                }
            }
        }
    }
}

// ---------------------------------------------------------------------------
// K2: threshold bucket via parallel suffix scans (no serial walk)
__global__ __launch_bounds__(1024) void k_thresh(const unsigned int* __restrict__ hist,
                                                 unsigned int* __restrict__ tb) {
    int b = blockIdx.x;
    const unsigned int* h = hist + b * 65536;
    __shared__ unsigned int scan[1024];
    __shared__ int cstar;
    int t = threadIdx.x;

    unsigned int acc = 0;
    const uint4* h4 = reinterpret_cast<const uint4*>(h + t * 64);
    #pragma unroll
    for (int i = 0; i < 16; ++i) { uint4 v = h4[i]; acc += v.x + v.y + v.z + v.w; }
    scan[t] = acc;
    if (t == 0) cstar = -1;
    __syncthreads();
    // suffix inclusive scan (Hillis-Steele)
    for (int d = 1; d < 1024; d <<= 1) {
        unsigned int v = (t + d < 1024) ? scan[t + d] : 0;
        __syncthreads();
        scan[t] += v;
        __syncthreads();
    }
    unsigned int Snext = (t < 1023) ? scan[t + 1] : 0;
    if (scan[t] >= TOPK && (t == 1023 || Snext < TOPK)) cstar = t;
    __syncthreads();
    int c = cstar;
    if (c < 0) {
        if (t == 0) tb[b] = 0;
        return;
    }
    if (t < 64) {   // wave 0: locate exact bin inside chunk c
        unsigned int above = (c < 1023) ? scan[c + 1] : 0;
        unsigned int suf = h[c * 64 + t];
        #pragma unroll
        for (int d = 1; d < 64; d <<= 1) {
            unsigned int v2 = __shfl_down(suf, d, 64);
            suf += (t + d < 64) ? v2 : 0;
        }
        bool cond = (above + suf) >= (unsigned int)TOPK;
        unsigned long long msk = __ballot(cond);
        if (t == 0) tb[b] = (unsigned int)(c * 64 + (63 - __clzll(msk)));
    }
}

// ---------------------------------------------------------------------------
// K3: collect candidates with bucket >= tb as (valbits<<32)|~pix
__global__ void k_collect(const float* __restrict__ nms, const unsigned int* __restrict__ tb,
                          unsigned long long* __restrict__ cand, unsigned int* __restrict__ cnt) {
    int t = blockIdx.x * blockDim.x + threadIdx.x;
    if (t >= NBATCH * NPIX) return;
    float v = nms[t];
    if (v > 0.0f) {
        int b = t >> 18;
        unsigned int key = __float_as_uint(v);
        if ((key >> 16) >= tb[b]) {
            unsigned int pos = atomicAdd(&cnt[b], 1u);
            if (pos < CAND_CAP) {
                unsigned int pix = (unsigned int)(t & (NPIX - 1));
                cand[b * CAND_CAP + pos] =
                    ((unsigned long long)key << 32) | (unsigned long long)(~pix);
            }
        }
    }
}

// ---------------------------------------------------------------------------
// K4: exact rank by counting (replaces bitonic sort). All keys in LDS;
// rank(i) = #{j : key_j > key_i}; distinct composites -> total order ==
// jax.lax.top_k order (ties on value break to smaller index via ~pix).
__global__ __launch_bounds__(256) void k_rank(const unsigned long long* __restrict__ cand,
                                              const unsigned int* __restrict__ cnt,
                                              int* __restrict__ kpts) {
    __shared__ unsigned long long sk[CAND_CAP];   // 32 KB
    int b = blockIdx.y;
    int tid = threadIdx.x;
    unsigned int n = cnt[b];
    if (n > CAND_CAP) n = CAND_CAP;
    const unsigned long long* cb = cand + b * CAND_CAP;
    for (int i = tid; i < CAND_CAP; i += 256)
        sk[i] = (i < (int)n) ? cb[i] : 0ULL;
    __syncthreads();
    int i = blockIdx.x * 256 + tid;
    if (i < (int)n) {
        unsigned long long my = sk[i];
        int rank = 0;
        int j = 0;
        int n4 = (int)n & ~3;
        for (; j < n4; j += 4) {
            rank += (sk[j] > my) + (sk[j + 1] > my) + (sk[j + 2] > my) + (sk[j + 3] > my);
        }
        for (; j < (int)n; ++j) rank += (sk[j] > my);
        if (rank < TOPK) {
            unsigned int pix = ~(unsigned int)(my & 0xFFFFFFFFULL);
            kpts[b * TOPK + rank] = (int)pix;
        }
    }
}

// ---------------------------------------------------------------------------
// K5: per-keypoint 5x5 soft-argmax, disp, normalized kxy, score bilinear, taps
__global__ void k_soft(const float* __restrict__ s, const int* __restrict__ kpts,
                       float* __restrict__ out_kxy, float* __restrict__ out_sc,
                       float* __restrict__ out_disp, Tap* __restrict__ taps) {
    int t = blockIdx.x * blockDim.x + threadIdx.x;
    if (t >= NBATCH * TOPK) return;
    int b = t >> 11;
    int pix = kpts[t];
    int ky = (pix >> 9) & 511, kx = pix & 511;
    const float* sb = s + (size_t)b * NPIX;

    float p[25];
    float maxv = -INFINITY;
    #pragma unroll
    for (int i = 0; i < 5; ++i)
        #pragma unroll
        for (int j = 0; j < 5; ++j) {
            float v = sb[(ky - 2 + i) * W + (kx - 2 + j)];
            p[i * 5 + j] = v;
            maxv = fmaxf(maxv, v);
        }
    float e[25];
    float ssum = 0.0f, sx = 0.0f, sy = 0.0f;
    #pragma unroll
    for (int i = 0; i < 5; ++i)
        #pragma unroll
        for (int j = 0; j < 5; ++j) {
            float ev = expf((p[i * 5 + j] - maxv) / 0.1f);
            e[i * 5 + j] = ev;
            ssum += ev;
            sx += ev * (float)(j - 2);
            sy += ev * (float)(i - 2);
        }
    float xr = sx / ssum, yr = sy / ssum;
    float acc = 0.0f;
    #pragma unroll
    for (int i = 0; i < 5; ++i)
        #pragma unroll
        for (int j = 0; j < 5; ++j) {
            float dx = ((float)(j - 2) - xr) * 0.5f;
            float dy = ((float)(i - 2) - yr) * 0.5f;
            acc += e[i * 5 + j] * (dx * dx + dy * dy);
        }
    float disp = acc / ssum;

    float nx = ((float)kx + xr) / 511.0f * 2.0f - 1.0f;
    float ny = ((float)ky + yr) / 511.0f * 2.0f - 1.0f;
    out_kxy[t * 2 + 0] = nx;
    out_kxy[t * 2 + 1] = ny;
    out_disp[t] = disp;

    float xp = (nx + 1.0f) * 0.5f * 511.0f;
    float yp = (ny + 1.0f) * 0.5f * 511.0f;
    float x0 = floorf(xp), y0 = floorf(yp);
    float wxf = xp - x0, wyf = yp - y0;
    int x0i = (int)fminf(fmaxf(x0, 0.0f), 511.0f);
    int x1i = (int)fminf(fmaxf(x0 + 1.0f, 0.0f), 511.0f);
    int y0i = (int)fminf(fmaxf(y0, 0.0f), 511.0f);
    int y1i = (int)fminf(fmaxf(y0 + 1.0f, 0.0f), 511.0f);
    float v00 = sb[y0i * W + x0i], v01 = sb[y0i * W + x1i];
    float v10 = sb[y1i * W + x0i], v11 = sb[y1i * W + x1i];
    out_sc[t] = v00 * (1.0f - wxf) * (1.0f - wyf) + v01 * wxf * (1.0f - wyf)
              + v10 * (1.0f - wxf) * wyf + v11 * wxf * wyf;

    Tap tp;
    tp.x0 = x0i; tp.x1 = x1i; tp.y0 = y0i; tp.y1 = y1i;
    tp.wx = wxf; tp.wy = wyf; tp.pad0 = 0.0f; tp.pad1 = 0.0f;
    taps[t] = tp;
}

// ---------------------------------------------------------------------------
// K6: one block per keypoint, 128 threads = 128 channels; bilinear + L2 norm
__global__ void k_desc(const float* __restrict__ dmap, const Tap* __restrict__ taps,
                       float* __restrict__ out_desc) {
    int t = blockIdx.x;          // 0..4095
    int b = t >> 11;
    int c = threadIdx.x;         // 0..127
    Tap tp = taps[t];
    const float* db = dmap + ((size_t)(b * 128 + c)) * NPIX;
    float w00 = (1.0f - tp.wx) * (1.0f - tp.wy);
    float w01 = tp.wx * (1.0f - tp.wy);
    float w10 = (1.0f - tp.wx) * tp.wy;
    float w11 = tp.wx * tp.wy;
    float v = db[tp.y0 * W + tp.x0] * w00 + db[tp.y0 * W + tp.x1] * w01
            + db[tp.y1 * W + tp.x0] * w10 + db[tp.y1 * W + tp.x1] * w11;

    float sq = v * v;
    #pragma unroll
    for (int m = 32; m >= 1; m >>= 1) sq += __shfl_xor(sq, m, 64);
    __shared__ float red[2];
    int wave = c >> 6, lane = c & 63;
    if (lane == 0) red[wave] = sq;
    __syncthreads();
    float tot = red[0] + red[1];
    float nrm = sqrtf(tot);
    float sc = 1.0f / fmaxf(nrm, 1e-12f);
    out_desc[(size_t)t * 128 + c] = v * sc;
}

extern "C" void kernel_launch(void* const* d_in, const int* in_sizes, int n_in,
                              void* d_out, int out_size, void* d_ws, size_t ws_size,
                              hipStream_t stream) {
    const float* s    = (const float*)d_in[0];   // (2,1,512,512)
    const float* dmap = (const float*)d_in[1];   // (2,128,512,512)
    float* out = (float*)d_out;
    float* out_kxy  = out;                          // 2*2048*2
    float* out_desc = out + 8192;                   // 2*2048*128
    float* out_sc   = out + 8192 + 524288;          // 2*2048
    float* out_disp = out_sc + 4096;                // 2*2048

    char* w = (char*)d_ws;
    float* nms           = (float*)w;          w += (size_t)NBATCH * NPIX * 4;
    unsigned int* hist   = (unsigned int*)w;   w += (size_t)NBATCH * 65536 * 4;
    unsigned long long* cand = (unsigned long long*)w; w += (size_t)NBATCH * CAND_CAP * 8;
    unsigned int* cnt    = (unsigned int*)w;   w += 256;
    unsigned int* tb     = (unsigned int*)w;   w += 256;
    int* kpts            = (int*)w;            w += (size_t)NBATCH * TOPK * 4;
    Tap* taps            = (Tap*)w;            w += (size_t)NBATCH * TOPK * sizeof(Tap);

    k_zero<<<dim3(512), dim3(256), 0, stream>>>(hist, cnt);
    k_nms_fused<<<dim3(16, 16, NBATCH), dim3(256), 0, stream>>>(s, nms, hist);
    k_thresh<<<dim3(NBATCH), dim3(1024), 0, stream>>>(hist, tb);
    k_collect<<<dim3((NBATCH * NPIX) / 256), dim3(256), 0, stream>>>(nms, tb, cand, cnt);
    k_rank<<<dim3(CAND_CAP / 256, NBATCH), dim3(256), 0, stream>>>(cand, cnt, kpts);
    k_soft<<<dim3((NBATCH * TOPK) / 256), dim3(256), 0, stream>>>(s, kpts, out_kxy, out_sc, out_disp, taps);
    k_desc<<<dim3(NBATCH * TOPK), dim3(128), 0, stream>>>(dmap, taps, out_desc);
}